// Round 3
// baseline (1229.621 us; speedup 1.0000x reference)
//
#include <hip/hip_runtime.h>

namespace {

constexpr int QN = 4;
constexpr int MR = 8192;   // B*S
constexpr int DD = 768;
constexpr int HH = 512;
constexpr int NN = 1024;
constexpr float DELTA = 0.008f;   // argmax tie-recheck threshold

typedef __attribute__((ext_vector_type(8))) __bf16 bf16x8;
typedef __attribute__((ext_vector_type(4))) __bf16 bf16x4;
typedef __attribute__((ext_vector_type(4))) float  f32x4;

#define GL2LDS(g, l) __builtin_amdgcn_global_load_lds( \
    (const __attribute__((address_space(1))) void*)(g), \
    (__attribute__((address_space(3))) void*)(l), 16, 0, 0)

// ------------- fused prep: 4 weight transposes + x fp32->bf16 -----------
// block ranges:
//   [0,1536)     pW1  [4][768][512]  -> w1t  [4][512][768]
//   [1536,3584)  pW2  [4][512][1024] -> w2t  [4][1024][512]
//   [3584,4736)  dW1  [768][1536]    -> dw1t [1536][768]
//   [4736,5888)  dW2  [1536][768]    -> dw2t [768][1536]
//   [5888,8960)  x fp32 -> Abf bf16 (row-major copy, 2048 elems/block)
__global__ __launch_bounds__(256)
void prep(const float* __restrict__ pW1, const float* __restrict__ pW2,
          const float* __restrict__ dW1, const float* __restrict__ dW2,
          const float* __restrict__ x,
          __bf16* __restrict__ w1t, __bf16* __restrict__ w2t,
          __bf16* __restrict__ dw1t, __bf16* __restrict__ dw2t,
          __bf16* __restrict__ Abf)
{
    const int id = blockIdx.x;
    const int t  = threadIdx.x;

    if (id >= 5888) {   // x conversion
        const size_t i = ((size_t)(id - 5888) * 256 + t) * 8;
        float4 a = *(const float4*)(x + i);
        float4 b = *(const float4*)(x + i + 4);
        bf16x8 o;
        o[0] = (__bf16)a.x; o[1] = (__bf16)a.y; o[2] = (__bf16)a.z; o[3] = (__bf16)a.w;
        o[4] = (__bf16)b.x; o[5] = (__bf16)b.y; o[6] = (__bf16)b.z; o[7] = (__bf16)b.w;
        *(bf16x8*)(Abf + i) = o;
        return;
    }

    __shared__ float tile[32][33];
    const float* src; __bf16* dst; int K, N; size_t bo; int k0, n0;
    if (id < 1536) {
        int b = id / 384, rm = id % 384;
        src = pW1; dst = w1t; K = 768; N = 512;
        bo = (size_t)b * K * N; n0 = (rm & 15) * 32; k0 = (rm >> 4) * 32;
    } else if (id < 3584) {
        int q = id - 1536; int b = q / 512, rm = q % 512;
        src = pW2; dst = w2t; K = 512; N = 1024;
        bo = (size_t)b * K * N; n0 = (rm & 31) * 32; k0 = (rm >> 5) * 32;
    } else if (id < 4736) {
        int rm = id - 3584;
        src = dW1; dst = dw1t; K = 768; N = 1536;
        bo = 0; n0 = (rm % 48) * 32; k0 = (rm / 48) * 32;
    } else {
        int rm = id - 4736;
        src = dW2; dst = dw2t; K = 1536; N = 768;
        bo = 0; n0 = (rm % 24) * 32; k0 = (rm / 24) * 32;
    }
    const int tx = t & 31, ty = t >> 5;   // 32 x 8
    #pragma unroll
    for (int i = 0; i < 4; ++i)
        tile[ty + 8 * i][tx] = src[bo + (size_t)(k0 + ty + 8 * i) * N + n0 + tx];
    __syncthreads();
    #pragma unroll
    for (int i = 0; i < 4; ++i)
        dst[bo + (size_t)(n0 + ty + 8 * i) * K + k0 + tx] = (__bf16)tile[tx][ty + 8 * i];
}

// ------------- MFMA GEMM + BN(eval) + ReLU ------------------------------
// Depth-2 pipelined k-loop: 3 LDS buffers, raw s_barrier, counted vmcnt.
template<int OUTBF>
__global__ __launch_bounds__(256)
void gemm_mfma(const __bf16* __restrict__ A, const __bf16* __restrict__ BT,
               const float* __restrict__ bias, const float* __restrict__ gam,
               const float* __restrict__ beta, const float* __restrict__ mean,
               const float* __restrict__ var,
               float* __restrict__ C32, __bf16* __restrict__ Cbf,
               int N_, int K_)
{
    __shared__ __bf16 smem[24576];         // 3 buffers × (As 4096 | Bs 4096) = 48 KB

    const int t   = threadIdx.x;
    const int bn0 = blockIdx.x * 128;
    const int bm0 = blockIdx.y * 128;
    const int l    = t & 63, w = t >> 6;
    const int lm   = l & 15, quad = l >> 4;
    const int mrow = (w & 1) * 64, ncol = (w >> 1) * 64;

    const int sA0 = t, sA1 = t + 256;
    const int mA0 = sA0 >> 2, qA0 = ((sA0 & 3) - (mA0 >> 1)) & 3;
    const int mA1 = sA1 >> 2, qA1 = ((sA1 & 3) - (mA1 >> 1)) & 3;
    const size_t gA0 = (size_t)(bm0 + mA0) * K_ + qA0 * 8;
    const size_t gA1 = (size_t)(bm0 + mA1) * K_ + qA1 * 8;
    const size_t gB0 = (size_t)(bn0 + mA0) * K_ + qA0 * 8;
    const size_t gB1 = (size_t)(bn0 + mA1) * K_ + qA1 * 8;

    f32x4 acc[4][4] = {};

    int aslot[4], bslot[4];
    #pragma unroll
    for (int i = 0; i < 4; ++i) {
        int m = mrow + i * 16 + lm;
        aslot[i] = m * 4 + ((quad + (m >> 1)) & 3);
        int n = ncol + i * 16 + lm;
        bslot[i] = n * 4 + ((quad + (n >> 1)) & 3);
    }

    const int nk = K_ >> 5;   // K_/32, always >= 16 here

    // prologue: stage tiles 0 and 1 into buffers 0 and 1
    {
        __bf16* As = smem;
        __bf16* Bs = smem + 4096;
        GL2LDS(A  + gA0, As + sA0 * 8);
        GL2LDS(A  + gA1, As + sA1 * 8);
        GL2LDS(BT + gB0, Bs + sA0 * 8);
        GL2LDS(BT + gB1, Bs + sA1 * 8);
        As = smem + 8192;
        Bs = As + 4096;
        GL2LDS(A  + gA0 + 32, As + sA0 * 8);
        GL2LDS(A  + gA1 + 32, As + sA1 * 8);
        GL2LDS(BT + gB0 + 32, Bs + sA0 * 8);
        GL2LDS(BT + gB1 + 32, Bs + sA1 * 8);
    }

    int bc = 0;   // buffer index of the tile being computed
    for (int ks = 0; ks < nk; ++ks) {
        if (ks + 1 < nk) asm volatile("s_waitcnt vmcnt(4)" ::: "memory");
        else             asm volatile("s_waitcnt vmcnt(0)" ::: "memory");
        __builtin_amdgcn_s_barrier();
        asm volatile("" ::: "memory");

        // stage tile ks+2 into the buffer vacated by tile ks-1
        if (ks + 2 < nk) {
            int sb = bc + 2; if (sb >= 3) sb -= 3;
            __bf16* Asn = smem + sb * 8192;
            __bf16* Bsn = Asn + 4096;
            const size_t ko = (size_t)(ks + 2) * 32;
            GL2LDS(A  + gA0 + ko, Asn + sA0 * 8);
            GL2LDS(A  + gA1 + ko, Asn + sA1 * 8);
            GL2LDS(BT + gB0 + ko, Bsn + sA0 * 8);
            GL2LDS(BT + gB1 + ko, Bsn + sA1 * 8);
        }

        const __bf16* As = smem + bc * 8192;
        const __bf16* Bs = As + 4096;
        bf16x8 af[4], bfv[4];
        #pragma unroll
        for (int i = 0; i < 4; ++i) {
            af[i]  = *(const bf16x8*)(As + aslot[i] * 8);
            bfv[i] = *(const bf16x8*)(Bs + bslot[i] * 8);
        }
        #pragma unroll
        for (int mt = 0; mt < 4; ++mt)
            #pragma unroll
            for (int nt = 0; nt < 4; ++nt)
                acc[mt][nt] = __builtin_amdgcn_mfma_f32_16x16x32_bf16(
                    af[mt], bfv[nt], acc[mt][nt], 0, 0, 0);

        // my ds_reads retired -> next iteration may overwrite this buffer
        asm volatile("s_waitcnt lgkmcnt(0)" ::: "memory");
        bc = (bc == 2) ? 0 : bc + 1;
    }

    float sc[4], sh[4]; int cn[4];
    #pragma unroll
    for (int nt = 0; nt < 4; ++nt) {
        int c = bn0 + ncol + nt * 16 + lm;
        cn[nt] = c;
        float s = gam[c] * rsqrtf(var[c] + 1e-5f);
        sc[nt] = s;
        sh[nt] = (bias[c] - mean[c]) * s + beta[c];
    }
    #pragma unroll
    for (int mt = 0; mt < 4; ++mt) {
        int r0 = bm0 + mrow + mt * 16 + quad * 4;
        #pragma unroll
        for (int nt = 0; nt < 4; ++nt) {
            #pragma unroll
            for (int reg = 0; reg < 4; ++reg) {
                float v = fmaxf(0.f, fmaf(acc[mt][nt][reg], sc[nt], sh[nt]));
                size_t off = (size_t)(r0 + reg) * N_ + cn[nt];
                if (OUTBF) Cbf[off] = (__bf16)v;
                else       C32[off] = v;
            }
        }
    }
}

// ------------- per-row stats + inline fp32 recheck + fused gather -------
__global__ __launch_bounds__(256)
void row_stats(const float* __restrict__ z, const float* __restrict__ gum,
               float* __restrict__ ent, float* __restrict__ lat,
               float* __restrict__ idxf,
               const float* __restrict__ Ain, const float* __restrict__ cb,
               const float* __restrict__ W1, const float* __restrict__ b1,
               const float* __restrict__ g1, const float* __restrict__ be1,
               const float* __restrict__ m1, const float* __restrict__ v1,
               const float* __restrict__ W2, const float* __restrict__ b2,
               const float* __restrict__ g2, const float* __restrict__ be2,
               const float* __restrict__ m2, const float* __restrict__ v2,
               float* __restrict__ res, float* __restrict__ qout,
               __bf16* __restrict__ res_bf, __bf16* __restrict__ qo_bf,
               int first, int last)
{
    __shared__ float rowbuf[DD];
    __shared__ float hs[HH];
    __shared__ float sred[8];
    __shared__ int   sredi[4];
    __shared__ float stop1;
    __shared__ int   stop1i;
    __shared__ int   sflag;

    const int r   = blockIdx.x;
    const int t   = threadIdx.x;
    const int wid = t >> 6;
    const bool l0 = (t & 63) == 0;

    // stage the fp32 input row (used by gather; by fp32 recheck if flagged)
    if (t < 192)
        *(float4*)&rowbuf[t * 4] = *(const float4*)(Ain + (size_t)r * DD + t * 4);

    const float4 z4 = ((const float4*)(z   + (size_t)r * NN))[t];
    const float4 g4 = ((const float4*)(gum + (size_t)r * NN))[t];

    // softmax stats
    float mx = fmaxf(fmaxf(z4.x, z4.y), fmaxf(z4.z, z4.w));
    #pragma unroll
    for (int o = 1; o < 64; o <<= 1) mx = fmaxf(mx, __shfl_xor(mx, o, 64));
    if (l0) sred[wid] = mx;
    __syncthreads();
    mx = fmaxf(fmaxf(sred[0], sred[1]), fmaxf(sred[2], sred[3]));

    float e0 = __expf(z4.x - mx), e1 = __expf(z4.y - mx);
    float e2 = __expf(z4.z - mx), e3 = __expf(z4.w - mx);
    float s = (e0 + e1) + (e2 + e3);
    #pragma unroll
    for (int o = 1; o < 64; o <<= 1) s += __shfl_xor(s, o, 64);
    if (l0) sred[4 + wid] = s;
    __syncthreads();
    s = (sred[4] + sred[5]) + (sred[6] + sred[7]);

    const float inv = 1.0f / s;
    const float q0 = e0 * inv, q1 = e1 * inv, q2 = e2 * inv, q3 = e3 * inv;

    float ep = q0 * __logf(q0 + 1e-10f) + q1 * __logf(q1 + 1e-10f)
             + q2 * __logf(q2 + 1e-10f) + q3 * __logf(q3 + 1e-10f);
    #pragma unroll
    for (int o = 1; o < 64; o <<= 1) ep += __shfl_xor(ep, o, 64);

    float4 l4;
    l4.x = q0 * __logf(q0 * 1024.f + 1e-10f);
    l4.y = q1 * __logf(q1 * 1024.f + 1e-10f);
    l4.z = q2 * __logf(q2 * 1024.f + 1e-10f);
    l4.w = q3 * __logf(q3 * 1024.f + 1e-10f);
    ((float4*)(lat + (size_t)r * NN))[t] = l4;

    // argmax(z+g) top-1
    const float y0 = z4.x + g4.x, y1 = z4.y + g4.y;
    const float y2 = z4.z + g4.z, y3 = z4.w + g4.w;
    float bv = y0; int bi = t * 4;
    if (y1 > bv) { bv = y1; bi = t * 4 + 1; }
    if (y2 > bv) { bv = y2; bi = t * 4 + 2; }
    if (y3 > bv) { bv = y3; bi = t * 4 + 3; }
    #pragma unroll
    for (int o = 1; o < 64; o <<= 1) {
        float ov = __shfl_xor(bv, o, 64);
        int   oi = __shfl_xor(bi, o, 64);
        if (ov > bv || (ov == bv && oi < bi)) { bv = ov; bi = oi; }
    }
    __syncthreads();
    if (l0) { sred[wid] = ep; sred[4 + wid] = bv; sredi[wid] = bi; }
    __syncthreads();
    if (t == 0) {
        ent[r] = -((sred[0] + sred[1]) + (sred[2] + sred[3]));
        float bbv = sred[4]; int bbi = sredi[0];
        #pragma unroll
        for (int ww = 1; ww < 4; ++ww)
            if (sred[4 + ww] > bbv || (sred[4 + ww] == bbv && sredi[ww] < bbi)) {
                bbv = sred[4 + ww]; bbi = sredi[ww];
            }
        stop1 = bbv; stop1i = bbi;
    }
    __syncthreads();
    const float t1v = stop1;
    const int   t1i = stop1i;

    // top-2 (excluding top-1) for tie detection
    float ex = -1e30f;
    if (t * 4 + 0 != t1i) ex = y0;
    if (t * 4 + 1 != t1i) ex = fmaxf(ex, y1);
    if (t * 4 + 2 != t1i) ex = fmaxf(ex, y2);
    if (t * 4 + 3 != t1i) ex = fmaxf(ex, y3);
    #pragma unroll
    for (int o = 1; o < 64; o <<= 1) ex = fmaxf(ex, __shfl_xor(ex, o, 64));
    __syncthreads();
    if (l0) sred[wid] = ex;
    __syncthreads();
    if (t == 0) {
        float t2 = fmaxf(fmaxf(sred[0], sred[1]), fmaxf(sred[2], sred[3]));
        sflag = (t1v - t2 < DELTA) ? 1 : 0;
    }
    __syncthreads();

    int fidx = t1i;

    // ---- inline fp32 recompute when the bf16 argmax margin is ambiguous
    if (sflag) {
        // h = relu(bn(row @ W1 + b1)) — 2 outputs/thread, 16-deep load ILP
        #pragma unroll
        for (int jj = 0; jj < 2; ++jj) {
            const int j = t + jj * 256;
            float a0 = 0.f, a1 = 0.f, a2 = 0.f, a3 = 0.f;
            #pragma unroll 4
            for (int k = 0; k < DD; k += 4) {
                a0 = fmaf(rowbuf[k + 0], W1[(size_t)(k + 0) * HH + j], a0);
                a1 = fmaf(rowbuf[k + 1], W1[(size_t)(k + 1) * HH + j], a1);
                a2 = fmaf(rowbuf[k + 2], W1[(size_t)(k + 2) * HH + j], a2);
                a3 = fmaf(rowbuf[k + 3], W1[(size_t)(k + 3) * HH + j], a3);
            }
            float a = (a0 + a1) + (a2 + a3) + b1[j];
            float scl = g1[j] * rsqrtf(v1[j] + 1e-5f);
            hs[j] = fmaxf(0.f, (a - m1[j]) * scl + be1[j]);
        }
        __syncthreads();

        // z = relu(bn(h @ W2 + b2)); y = z + gumbel; block argmax
        float rbv = -1e30f; int rbi = 0;
        #pragma unroll
        for (int cc = 0; cc < 4; ++cc) {
            const int c = t + cc * 256;
            float a0 = 0.f, a1 = 0.f, a2 = 0.f, a3 = 0.f;
            #pragma unroll 4
            for (int j = 0; j < HH; j += 4) {
                a0 = fmaf(hs[j + 0], W2[(size_t)(j + 0) * NN + c], a0);
                a1 = fmaf(hs[j + 1], W2[(size_t)(j + 1) * NN + c], a1);
                a2 = fmaf(hs[j + 2], W2[(size_t)(j + 2) * NN + c], a2);
                a3 = fmaf(hs[j + 3], W2[(size_t)(j + 3) * NN + c], a3);
            }
            float a = (a0 + a1) + (a2 + a3) + b2[c];
            float scl = g2[c] * rsqrtf(v2[c] + 1e-5f);
            float zc  = fmaxf(0.f, (a - m2[c]) * scl + be2[c]);
            float y   = zc + gum[(size_t)r * NN + c];
            if (y > rbv || (y == rbv && c < rbi)) { rbv = y; rbi = c; }
        }
        #pragma unroll
        for (int o = 1; o < 64; o <<= 1) {
            float ov = __shfl_xor(rbv, o, 64);
            int   oi = __shfl_xor(rbi, o, 64);
            if (ov > rbv || (ov == rbv && oi < rbi)) { rbv = ov; rbi = oi; }
        }
        if (l0) { sred[wid] = rbv; sredi[wid] = rbi; }
        __syncthreads();
        if (t == 0) {
            float bbv = sred[0]; int bbi = sredi[0];
            #pragma unroll
            for (int ww = 1; ww < 4; ++ww)
                if (sred[ww] > bbv || (sred[ww] == bbv && sredi[ww] < bbi)) {
                    bbv = sred[ww]; bbi = sredi[ww];
                }
            stop1i = bbi;
        }
        __syncthreads();
        fidx = stop1i;
    }

    if (t == 0) idxf[r] = (float)fidx;

    // fused gather with the verified index; rowbuf holds the fp32 input row
    if (t < 192) {
        float4 c4 = *(const float4*)(cb + (size_t)fidx * DD + t * 4);
        float4 xv = *(const float4*)&rowbuf[t * 4];
        float4 rv, qv;
        rv.x = xv.x - c4.x; rv.y = xv.y - c4.y;
        rv.z = xv.z - c4.z; rv.w = xv.w - c4.w;
        if (first) { qv = c4; }
        else {
            qv = *(const float4*)(qout + (size_t)r * DD + t * 4);
            qv.x += c4.x; qv.y += c4.y; qv.z += c4.z; qv.w += c4.w;
        }
        if (!last) {
            *(float4*)(res  + (size_t)r * DD + t * 4) = rv;
            *(float4*)(qout + (size_t)r * DD + t * 4) = qv;
            bf16x4 rb;
            rb[0] = (__bf16)rv.x; rb[1] = (__bf16)rv.y;
            rb[2] = (__bf16)rv.z; rb[3] = (__bf16)rv.w;
            *(bf16x4*)(res_bf + (size_t)r * DD + t * 4) = rb;
        } else {
            bf16x4 qb;
            qb[0] = (__bf16)qv.x; qb[1] = (__bf16)qv.y;
            qb[2] = (__bf16)qv.z; qb[3] = (__bf16)qv.w;
            *(bf16x4*)(qo_bf + (size_t)r * DD + t * 4) = qb;
        }
    }
}

} // namespace

extern "C" void kernel_launch(void* const* d_in, const int* in_sizes, int n_in,
                              void* d_out, int out_size, void* d_ws, size_t ws_size,
                              hipStream_t stream)
{
    const float* x    = (const float*)d_in[0];
    const float* cb   = (const float*)d_in[1];
    const float* pW1  = (const float*)d_in[2];
    const float* pb1  = (const float*)d_in[3];
    const float* pg1  = (const float*)d_in[4];
    const float* pbe1 = (const float*)d_in[5];
    const float* pm1  = (const float*)d_in[6];
    const float* pv1  = (const float*)d_in[7];
    const float* pW2  = (const float*)d_in[8];
    const float* pb2  = (const float*)d_in[9];
    const float* pg2  = (const float*)d_in[10];
    const float* pbe2 = (const float*)d_in[11];
    const float* pm2  = (const float*)d_in[12];
    const float* pv2  = (const float*)d_in[13];
    const float* dW1  = (const float*)d_in[14];
    const float* db1  = (const float*)d_in[15];
    const float* dg1  = (const float*)d_in[16];
    const float* dbe1 = (const float*)d_in[17];
    const float* dm1  = (const float*)d_in[18];
    const float* dv1  = (const float*)d_in[19];
    const float* dW2  = (const float*)d_in[20];
    const float* db2  = (const float*)d_in[21];
    const float* dg2  = (const float*)d_in[22];
    const float* dbe2 = (const float*)d_in[23];
    const float* dm2  = (const float*)d_in[24];
    const float* dv2  = (const float*)d_in[25];
    const float* gum  = (const float*)d_in[26];

    // output layout (floats): xhat | entropies | latent | indices | zs
    float* out  = (float*)d_out;
    float* xhat = out;
    float* ent  = xhat + (size_t)MR * DD;
    float* lat  = ent  + (size_t)QN * MR;
    float* idxf = lat  + (size_t)QN * MR * NN;
    float* zs   = idxf + (size_t)QN * MR;

    // workspace layout
    char* wp = (char*)d_ws;
    float*  res   = (float*)wp;                 wp += (size_t)MR * DD * 4;
    float*  qo    = (float*)wp;                 wp += (size_t)MR * DD * 4;
    __bf16* Abf   = (__bf16*)wp;                wp += (size_t)MR * DD * 2;
    __bf16* hbf   = (__bf16*)wp;                wp += (size_t)MR * HH * 2;
    __bf16* qobf  = (__bf16*)wp;                wp += (size_t)MR * DD * 2;
    __bf16* h1bf  = (__bf16*)wp;                wp += (size_t)MR * 2 * DD * 2;
    __bf16* w1t   = (__bf16*)wp;                wp += (size_t)QN * DD * HH * 2;
    __bf16* w2t   = (__bf16*)wp;                wp += (size_t)QN * HH * NN * 2;
    __bf16* dw1t  = (__bf16*)wp;                wp += (size_t)DD * 2 * DD * 2;
    __bf16* dw2t  = (__bf16*)wp;                wp += (size_t)2 * DD * DD * 2;

    dim3 b256(256);

    // fused prep: all weight transposes + x conversion in one launch
    hipLaunchKernelGGL(prep, dim3(8960), b256, 0, stream,
        pW1, pW2, dW1, dW2, x, w1t, w2t, dw1t, dw2t, Abf);

    for (int i = 0; i < QN; ++i) {
        const int first = (i == 0), last = (i == QN - 1);
        hipLaunchKernelGGL((gemm_mfma<1>), dim3(HH / 128, MR / 128), b256, 0, stream,
            Abf, w1t + (size_t)i * DD * HH,
            pb1 + i * HH, pg1 + i * HH, pbe1 + i * HH, pm1 + i * HH, pv1 + i * HH,
            (float*)nullptr, hbf, HH, DD);
        float* z_i = zs + (size_t)i * MR * NN;
        hipLaunchKernelGGL((gemm_mfma<0>), dim3(NN / 128, MR / 128), b256, 0, stream,
            hbf, w2t + (size_t)i * HH * NN,
            pb2 + i * NN, pg2 + i * NN, pbe2 + i * NN, pm2 + i * NN, pv2 + i * NN,
            z_i, (__bf16*)nullptr, NN, HH);

        const float* Ain = (i == 0) ? x : res;
        hipLaunchKernelGGL(row_stats, dim3(MR), b256, 0, stream,
            z_i, gum + (size_t)i * MR * NN,
            ent + (size_t)i * MR, lat + (size_t)i * MR * NN, idxf + (size_t)i * MR,
            Ain, cb + (size_t)i * NN * DD,
            pW1 + (size_t)i * DD * HH, pb1 + i * HH, pg1 + i * HH, pbe1 + i * HH,
            pm1 + i * HH, pv1 + i * HH,
            pW2 + (size_t)i * HH * NN, pb2 + i * NN, pg2 + i * NN, pbe2 + i * NN,
            pm2 + i * NN, pv2 + i * NN,
            res, qo, Abf, qobf, first, last);
    }
    // decoder
    hipLaunchKernelGGL((gemm_mfma<1>), dim3(2 * DD / 128, MR / 128), b256, 0, stream,
        qobf, dw1t, db1, dg1, dbe1, dm1, dv1, (float*)nullptr, h1bf, 2 * DD, DD);
    hipLaunchKernelGGL((gemm_mfma<0>), dim3(DD / 128, MR / 128), b256, 0, stream,
        h1bf, dw2t, db2, dg2, dbe2, dm2, dv2, xhat, (__bf16*)nullptr, DD, 2 * DD);
}

// Round 5
// 1203.068 us; speedup vs baseline: 1.0221x; 1.0221x over previous
//
#include <hip/hip_runtime.h>

namespace {

constexpr int QN = 4;
constexpr int MR = 8192;   // B*S
constexpr int DD = 768;
constexpr int HH = 512;
constexpr int NN = 1024;
constexpr float DELTA = 0.008f;   // argmax tie-recheck threshold

typedef __attribute__((ext_vector_type(8))) __bf16 bf16x8;
typedef __attribute__((ext_vector_type(4))) __bf16 bf16x4;
typedef __attribute__((ext_vector_type(4))) float  f32x4;

#define GL2LDS(g, l) __builtin_amdgcn_global_load_lds( \
    (const __attribute__((address_space(1))) void*)(g), \
    (__attribute__((address_space(3))) void*)(l), 16, 0, 0)

// ------------- fused prep: 4 weight transposes + x fp32->bf16 + cnt=0 ---
// block ranges:
//   [0,1536)     pW1  [4][768][512]  -> w1t  [4][512][768]
//   [1536,3584)  pW2  [4][512][1024] -> w2t  [4][1024][512]
//   [3584,4736)  dW1  [768][1536]    -> dw1t [1536][768]
//   [4736,5888)  dW2  [1536][768]    -> dw2t [768][1536]
//   [5888,8960)  x fp32 -> Abf bf16 (row-major copy, 2048 elems/block)
__global__ __launch_bounds__(256)
void prep(const float* __restrict__ pW1, const float* __restrict__ pW2,
          const float* __restrict__ dW1, const float* __restrict__ dW2,
          const float* __restrict__ x,
          __bf16* __restrict__ w1t, __bf16* __restrict__ w2t,
          __bf16* __restrict__ dw1t, __bf16* __restrict__ dw2t,
          __bf16* __restrict__ Abf, int* __restrict__ cnt)
{
    const int id = blockIdx.x;
    const int t  = threadIdx.x;

    if (id == 0 && t < QN) cnt[t] = 0;

    if (id >= 5888) {   // x conversion
        const size_t i = ((size_t)(id - 5888) * 256 + t) * 8;
        float4 a = *(const float4*)(x + i);
        float4 b = *(const float4*)(x + i + 4);
        bf16x8 o;
        o[0] = (__bf16)a.x; o[1] = (__bf16)a.y; o[2] = (__bf16)a.z; o[3] = (__bf16)a.w;
        o[4] = (__bf16)b.x; o[5] = (__bf16)b.y; o[6] = (__bf16)b.z; o[7] = (__bf16)b.w;
        *(bf16x8*)(Abf + i) = o;
        return;
    }

    __shared__ float tile[32][33];
    const float* src; __bf16* dst; int K, N; size_t bo; int k0, n0;
    if (id < 1536) {
        int b = id / 384, rm = id % 384;
        src = pW1; dst = w1t; K = 768; N = 512;
        bo = (size_t)b * K * N; n0 = (rm & 15) * 32; k0 = (rm >> 4) * 32;
    } else if (id < 3584) {
        int q = id - 1536; int b = q / 512, rm = q % 512;
        src = pW2; dst = w2t; K = 512; N = 1024;
        bo = (size_t)b * K * N; n0 = (rm & 31) * 32; k0 = (rm >> 5) * 32;
    } else if (id < 4736) {
        int rm = id - 3584;
        src = dW1; dst = dw1t; K = 768; N = 1536;
        bo = 0; n0 = (rm % 48) * 32; k0 = (rm / 48) * 32;
    } else {
        int rm = id - 4736;
        src = dW2; dst = dw2t; K = 1536; N = 768;
        bo = 0; n0 = (rm % 24) * 32; k0 = (rm / 24) * 32;
    }
    const int tx = t & 31, ty = t >> 5;   // 32 x 8
    #pragma unroll
    for (int i = 0; i < 4; ++i)
        tile[ty + 8 * i][tx] = src[bo + (size_t)(k0 + ty + 8 * i) * N + n0 + tx];
    __syncthreads();
    #pragma unroll
    for (int i = 0; i < 4; ++i)
        dst[bo + (size_t)(n0 + ty + 8 * i) * K + k0 + tx] = (__bf16)tile[tx][ty + 8 * i];
}

// ------------- MFMA GEMM + BN(eval) + ReLU ------------------------------
// Depth-2 pipelined k-loop: 3 LDS buffers, raw s_barrier, counted vmcnt.
template<int OUTBF>
__global__ __launch_bounds__(256)
void gemm_mfma(const __bf16* __restrict__ A, const __bf16* __restrict__ BT,
               const float* __restrict__ bias, const float* __restrict__ gam,
               const float* __restrict__ beta, const float* __restrict__ mean,
               const float* __restrict__ var,
               float* __restrict__ C32, __bf16* __restrict__ Cbf,
               int N_, int K_)
{
    __shared__ __bf16 smem[24576];         // 3 buffers × (As 4096 | Bs 4096) = 48 KB

    const int t   = threadIdx.x;
    const int bn0 = blockIdx.x * 128;
    const int bm0 = blockIdx.y * 128;
    const int l    = t & 63, w = t >> 6;
    const int lm   = l & 15, quad = l >> 4;
    const int mrow = (w & 1) * 64, ncol = (w >> 1) * 64;

    const int sA0 = t, sA1 = t + 256;
    const int mA0 = sA0 >> 2, qA0 = ((sA0 & 3) - (mA0 >> 1)) & 3;
    const int mA1 = sA1 >> 2, qA1 = ((sA1 & 3) - (mA1 >> 1)) & 3;
    const size_t gA0 = (size_t)(bm0 + mA0) * K_ + qA0 * 8;
    const size_t gA1 = (size_t)(bm0 + mA1) * K_ + qA1 * 8;
    const size_t gB0 = (size_t)(bn0 + mA0) * K_ + qA0 * 8;
    const size_t gB1 = (size_t)(bn0 + mA1) * K_ + qA1 * 8;

    f32x4 acc[4][4] = {};

    int aslot[4], bslot[4];
    #pragma unroll
    for (int i = 0; i < 4; ++i) {
        int m = mrow + i * 16 + lm;
        aslot[i] = m * 4 + ((quad + (m >> 1)) & 3);
        int n = ncol + i * 16 + lm;
        bslot[i] = n * 4 + ((quad + (n >> 1)) & 3);
    }

    const int nk = K_ >> 5;   // K_/32, always >= 16 here

    // prologue: stage tiles 0 and 1 into buffers 0 and 1
    {
        __bf16* As = smem;
        __bf16* Bs = smem + 4096;
        GL2LDS(A  + gA0, As + sA0 * 8);
        GL2LDS(A  + gA1, As + sA1 * 8);
        GL2LDS(BT + gB0, Bs + sA0 * 8);
        GL2LDS(BT + gB1, Bs + sA1 * 8);
        As = smem + 8192;
        Bs = As + 4096;
        GL2LDS(A  + gA0 + 32, As + sA0 * 8);
        GL2LDS(A  + gA1 + 32, As + sA1 * 8);
        GL2LDS(BT + gB0 + 32, Bs + sA0 * 8);
        GL2LDS(BT + gB1 + 32, Bs + sA1 * 8);
    }

    int bc = 0;   // buffer index of the tile being computed
    for (int ks = 0; ks < nk; ++ks) {
        if (ks + 1 < nk) asm volatile("s_waitcnt vmcnt(4)" ::: "memory");
        else             asm volatile("s_waitcnt vmcnt(0)" ::: "memory");
        __builtin_amdgcn_s_barrier();
        asm volatile("" ::: "memory");

        // stage tile ks+2 into the buffer vacated by tile ks-1
        if (ks + 2 < nk) {
            int sb = bc + 2; if (sb >= 3) sb -= 3;
            __bf16* Asn = smem + sb * 8192;
            __bf16* Bsn = Asn + 4096;
            const size_t ko = (size_t)(ks + 2) * 32;
            GL2LDS(A  + gA0 + ko, Asn + sA0 * 8);
            GL2LDS(A  + gA1 + ko, Asn + sA1 * 8);
            GL2LDS(BT + gB0 + ko, Bsn + sA0 * 8);
            GL2LDS(BT + gB1 + ko, Bsn + sA1 * 8);
        }

        const __bf16* As = smem + bc * 8192;
        const __bf16* Bs = As + 4096;
        bf16x8 af[4], bfv[4];
        #pragma unroll
        for (int i = 0; i < 4; ++i) {
            af[i]  = *(const bf16x8*)(As + aslot[i] * 8);
            bfv[i] = *(const bf16x8*)(Bs + bslot[i] * 8);
        }
        #pragma unroll
        for (int mt = 0; mt < 4; ++mt)
            #pragma unroll
            for (int nt = 0; nt < 4; ++nt)
                acc[mt][nt] = __builtin_amdgcn_mfma_f32_16x16x32_bf16(
                    af[mt], bfv[nt], acc[mt][nt], 0, 0, 0);

        // my ds_reads retired -> next iteration may overwrite this buffer
        asm volatile("s_waitcnt lgkmcnt(0)" ::: "memory");
        bc = (bc == 2) ? 0 : bc + 1;
    }

    float sc[4], sh[4]; int cn[4];
    #pragma unroll
    for (int nt = 0; nt < 4; ++nt) {
        int c = bn0 + ncol + nt * 16 + lm;
        cn[nt] = c;
        float s = gam[c] * rsqrtf(var[c] + 1e-5f);
        sc[nt] = s;
        sh[nt] = (bias[c] - mean[c]) * s + beta[c];
    }
    #pragma unroll
    for (int mt = 0; mt < 4; ++mt) {
        int r0 = bm0 + mrow + mt * 16 + quad * 4;
        #pragma unroll
        for (int nt = 0; nt < 4; ++nt) {
            #pragma unroll
            for (int reg = 0; reg < 4; ++reg) {
                float v = fmaxf(0.f, fmaf(acc[mt][nt][reg], sc[nt], sh[nt]));
                size_t off = (size_t)(r0 + reg) * N_ + cn[nt];
                if (OUTBF) Cbf[off] = (__bf16)v;
                else       C32[off] = v;
            }
        }
    }
}

// ------------- per-row stats + fused gather (unflagged rows) ------------
__global__ __launch_bounds__(256)
void row_stats(const float* __restrict__ z, const float* __restrict__ gum,
               float* __restrict__ ent, float* __restrict__ lat,
               float* __restrict__ idxf,
               int* __restrict__ wl, int* __restrict__ cnt,
               const float* __restrict__ Ain, const float* __restrict__ cb,
               float* __restrict__ res, float* __restrict__ qout,
               __bf16* __restrict__ res_bf, __bf16* __restrict__ qo_bf,
               int first, int last)
{
    __shared__ float sred[8];
    __shared__ int   sredi[4];
    __shared__ float stop1;
    __shared__ int   stop1i;
    __shared__ int   sflag;

    const int r   = blockIdx.x;
    const int t   = threadIdx.x;
    const int wid = t >> 6;
    const bool l0 = (t & 63) == 0;

    const float4 z4 = ((const float4*)(z   + (size_t)r * NN))[t];
    const float4 g4 = ((const float4*)(gum + (size_t)r * NN))[t];

    // softmax stats
    float mx = fmaxf(fmaxf(z4.x, z4.y), fmaxf(z4.z, z4.w));
    #pragma unroll
    for (int o = 1; o < 64; o <<= 1) mx = fmaxf(mx, __shfl_xor(mx, o, 64));
    if (l0) sred[wid] = mx;
    __syncthreads();
    mx = fmaxf(fmaxf(sred[0], sred[1]), fmaxf(sred[2], sred[3]));

    float e0 = __expf(z4.x - mx), e1 = __expf(z4.y - mx);
    float e2 = __expf(z4.z - mx), e3 = __expf(z4.w - mx);
    float s = (e0 + e1) + (e2 + e3);
    #pragma unroll
    for (int o = 1; o < 64; o <<= 1) s += __shfl_xor(s, o, 64);
    if (l0) sred[4 + wid] = s;
    __syncthreads();
    s = (sred[4] + sred[5]) + (sred[6] + sred[7]);

    const float inv = 1.0f / s;
    const float q0 = e0 * inv, q1 = e1 * inv, q2 = e2 * inv, q3 = e3 * inv;

    float ep = q0 * __logf(q0 + 1e-10f) + q1 * __logf(q1 + 1e-10f)
             + q2 * __logf(q2 + 1e-10f) + q3 * __logf(q3 + 1e-10f);
    #pragma unroll
    for (int o = 1; o < 64; o <<= 1) ep += __shfl_xor(ep, o, 64);

    float4 l4;
    l4.x = q0 * __logf(q0 * 1024.f + 1e-10f);
    l4.y = q1 * __logf(q1 * 1024.f + 1e-10f);
    l4.z = q2 * __logf(q2 * 1024.f + 1e-10f);
    l4.w = q3 * __logf(q3 * 1024.f + 1e-10f);
    ((float4*)(lat + (size_t)r * NN))[t] = l4;

    // argmax(z+g) top-1
    const float y0 = z4.x + g4.x, y1 = z4.y + g4.y;
    const float y2 = z4.z + g4.z, y3 = z4.w + g4.w;
    float bv = y0; int bi = t * 4;
    if (y1 > bv) { bv = y1; bi = t * 4 + 1; }
    if (y2 > bv) { bv = y2; bi = t * 4 + 2; }
    if (y3 > bv) { bv = y3; bi = t * 4 + 3; }
    #pragma unroll
    for (int o = 1; o < 64; o <<= 1) {
        float ov = __shfl_xor(bv, o, 64);
        int   oi = __shfl_xor(bi, o, 64);
        if (ov > bv || (ov == bv && oi < bi)) { bv = ov; bi = oi; }
    }
    __syncthreads();
    if (l0) { sred[wid] = ep; sred[4 + wid] = bv; sredi[wid] = bi; }
    __syncthreads();
    if (t == 0) {
        ent[r] = -((sred[0] + sred[1]) + (sred[2] + sred[3]));
        float bbv = sred[4]; int bbi = sredi[0];
        #pragma unroll
        for (int ww = 1; ww < 4; ++ww)
            if (sred[4 + ww] > bbv || (sred[4 + ww] == bbv && sredi[ww] < bbi)) {
                bbv = sred[4 + ww]; bbi = sredi[ww];
            }
        stop1 = bbv; stop1i = bbi;
    }
    __syncthreads();
    const float t1v = stop1;
    const int   t1i = stop1i;

    // top-2 (excluding top-1) for tie detection
    float ex = -1e30f;
    if (t * 4 + 0 != t1i) ex = y0;
    if (t * 4 + 1 != t1i) ex = fmaxf(ex, y1);
    if (t * 4 + 2 != t1i) ex = fmaxf(ex, y2);
    if (t * 4 + 3 != t1i) ex = fmaxf(ex, y3);
    #pragma unroll
    for (int o = 1; o < 64; o <<= 1) ex = fmaxf(ex, __shfl_xor(ex, o, 64));
    __syncthreads();
    if (l0) sred[wid] = ex;
    __syncthreads();
    if (t == 0) {
        idxf[r] = (float)t1i;
        float t2 = fmaxf(fmaxf(sred[0], sred[1]), fmaxf(sred[2], sred[3]));
        int fl = (t1v - t2 < DELTA) ? 1 : 0;
        sflag = fl;
        if (fl) { int p = atomicAdd(cnt, 1); wl[p] = r; }
    }
    __syncthreads();

    // fused gather: only when argmax is unambiguous (else recheck does it)
    if (!sflag && t < 192) {
        float4 c4 = *(const float4*)(cb + (size_t)t1i * DD + t * 4);
        float4 xv = *(const float4*)(Ain + (size_t)r * DD + t * 4);
        float4 rv, qv;
        rv.x = xv.x - c4.x; rv.y = xv.y - c4.y;
        rv.z = xv.z - c4.z; rv.w = xv.w - c4.w;
        if (first) { qv = c4; }
        else {
            qv = *(const float4*)(qout + (size_t)r * DD + t * 4);
            qv.x += c4.x; qv.y += c4.y; qv.z += c4.z; qv.w += c4.w;
        }
        if (!last) {
            *(float4*)(res  + (size_t)r * DD + t * 4) = rv;
            *(float4*)(qout + (size_t)r * DD + t * 4) = qv;
            bf16x4 rb;
            rb[0] = (__bf16)rv.x; rb[1] = (__bf16)rv.y;
            rb[2] = (__bf16)rv.z; rb[3] = (__bf16)rv.w;
            *(bf16x4*)(res_bf + (size_t)r * DD + t * 4) = rb;
        } else {
            bf16x4 qb;
            qb[0] = (__bf16)qv.x; qb[1] = (__bf16)qv.y;
            qb[2] = (__bf16)qv.z; qb[3] = (__bf16)qv.w;
            *(bf16x4*)(qo_bf + (size_t)r * DD + t * 4) = qb;
        }
    }
}

// ------------- fp32 recompute of flagged rows + their gather ------------
__global__ __launch_bounds__(256)
void recheck(const int* __restrict__ wl, const int* __restrict__ cnt,
             const float* __restrict__ gum, const float* __restrict__ Ain,
             const float* __restrict__ W1, const float* __restrict__ b1,
             const float* __restrict__ g1, const float* __restrict__ be1,
             const float* __restrict__ m1, const float* __restrict__ v1,
             const float* __restrict__ W2, const float* __restrict__ b2,
             const float* __restrict__ g2, const float* __restrict__ be2,
             const float* __restrict__ m2, const float* __restrict__ v2,
             float* __restrict__ idxf,
             const float* __restrict__ cb,
             float* __restrict__ res, float* __restrict__ qout,
             __bf16* __restrict__ res_bf, __bf16* __restrict__ qo_bf,
             int first, int last)
{
    __shared__ float rowbuf[DD];
    __shared__ float hs[HH];
    __shared__ float sred[4];
    __shared__ int   sredi[4];

    const int t   = threadIdx.x;
    const int wid = t >> 6;
    const bool l0 = (t & 63) == 0;
    const int n = cnt[0];

    for (int w = blockIdx.x; w < n; w += gridDim.x) {
        const int r = wl[w];
        __syncthreads();   // protect rowbuf/hs/sredi from previous iteration
        if (t < 192)
            *(float4*)&rowbuf[t * 4] = *(const float4*)(Ain + (size_t)r * DD + t * 4);
        __syncthreads();

        // h = relu(bn(row @ W1 + b1)) — 2 outputs/thread, 16-deep load ILP
        #pragma unroll
        for (int jj = 0; jj < 2; ++jj) {
            const int j = t + jj * 256;
            float a0 = 0.f, a1 = 0.f, a2 = 0.f, a3 = 0.f;
            #pragma unroll 4
            for (int k = 0; k < DD; k += 4) {
                a0 = fmaf(rowbuf[k + 0], W1[(size_t)(k + 0) * HH + j], a0);
                a1 = fmaf(rowbuf[k + 1], W1[(size_t)(k + 1) * HH + j], a1);
                a2 = fmaf(rowbuf[k + 2], W1[(size_t)(k + 2) * HH + j], a2);
                a3 = fmaf(rowbuf[k + 3], W1[(size_t)(k + 3) * HH + j], a3);
            }
            float a = (a0 + a1) + (a2 + a3) + b1[j];
            float scl = g1[j] * rsqrtf(v1[j] + 1e-5f);
            hs[j] = fmaxf(0.f, (a - m1[j]) * scl + be1[j]);
        }
        __syncthreads();

        // z = relu(bn(h @ W2 + b2)); y = z + gumbel; block argmax
        float bv = -1e30f; int bi = 0;
        #pragma unroll
        for (int cc = 0; cc < 4; ++cc) {
            const int c = t + cc * 256;
            float a0 = 0.f, a1 = 0.f, a2 = 0.f, a3 = 0.f;
            #pragma unroll 4
            for (int j = 0; j < HH; j += 4) {
                a0 = fmaf(hs[j + 0], W2[(size_t)(j + 0) * NN + c], a0);
                a1 = fmaf(hs[j + 1], W2[(size_t)(j + 1) * NN + c], a1);
                a2 = fmaf(hs[j + 2], W2[(size_t)(j + 2) * NN + c], a2);
                a3 = fmaf(hs[j + 3], W2[(size_t)(j + 3) * NN + c], a3);
            }
            float a = (a0 + a1) + (a2 + a3) + b2[c];
            float scl = g2[c] * rsqrtf(v2[c] + 1e-5f);
            float zc  = fmaxf(0.f, (a - m2[c]) * scl + be2[c]);
            float y   = zc + gum[(size_t)r * NN + c];
            if (y > bv || (y == bv && c < bi)) { bv = y; bi = c; }
        }
        #pragma unroll
        for (int o = 1; o < 64; o <<= 1) {
            float ov = __shfl_xor(bv, o, 64);
            int   oi = __shfl_xor(bi, o, 64);
            if (ov > bv || (ov == bv && oi < bi)) { bv = ov; bi = oi; }
        }
        if (l0) { sred[wid] = bv; sredi[wid] = bi; }
        __syncthreads();
        if (t == 0) {
            float bbv = sred[0]; int bbi = sredi[0];
            #pragma unroll
            for (int ww = 1; ww < 4; ++ww)
                if (sred[ww] > bbv || (sred[ww] == bbv && sredi[ww] < bbi)) {
                    bbv = sred[ww]; bbi = sredi[ww];
                }
            idxf[r] = (float)bbi;
            sredi[0] = bbi;
        }
        __syncthreads();

        // fused gather for this (flagged) row; rowbuf already holds Ain row
        const int ci = sredi[0];
        if (t < 192) {
            float4 c4 = *(const float4*)(cb + (size_t)ci * DD + t * 4);
            float4 xv = *(const float4*)&rowbuf[t * 4];
            float4 rv, qv;
            rv.x = xv.x - c4.x; rv.y = xv.y - c4.y;
            rv.z = xv.z - c4.z; rv.w = xv.w - c4.w;
            if (first) { qv = c4; }
            else {
                qv = *(const float4*)(qout + (size_t)r * DD + t * 4);
                qv.x += c4.x; qv.y += c4.y; qv.z += c4.z; qv.w += c4.w;
            }
            if (!last) {
                *(float4*)(res  + (size_t)r * DD + t * 4) = rv;
                *(float4*)(qout + (size_t)r * DD + t * 4) = qv;
                bf16x4 rb;
                rb[0] = (__bf16)rv.x; rb[1] = (__bf16)rv.y;
                rb[2] = (__bf16)rv.z; rb[3] = (__bf16)rv.w;
                *(bf16x4*)(res_bf + (size_t)r * DD + t * 4) = rb;
            } else {
                bf16x4 qb;
                qb[0] = (__bf16)qv.x; qb[1] = (__bf16)qv.y;
                qb[2] = (__bf16)qv.z; qb[3] = (__bf16)qv.w;
                *(bf16x4*)(qo_bf + (size_t)r * DD + t * 4) = qb;
            }
        }
    }
}

} // namespace

extern "C" void kernel_launch(void* const* d_in, const int* in_sizes, int n_in,
                              void* d_out, int out_size, void* d_ws, size_t ws_size,
                              hipStream_t stream)
{
    const float* x    = (const float*)d_in[0];
    const float* cb   = (const float*)d_in[1];
    const float* pW1  = (const float*)d_in[2];
    const float* pb1  = (const float*)d_in[3];
    const float* pg1  = (const float*)d_in[4];
    const float* pbe1 = (const float*)d_in[5];
    const float* pm1  = (const float*)d_in[6];
    const float* pv1  = (const float*)d_in[7];
    const float* pW2  = (const float*)d_in[8];
    const float* pb2  = (const float*)d_in[9];
    const float* pg2  = (const float*)d_in[10];
    const float* pbe2 = (const float*)d_in[11];
    const float* pm2  = (const float*)d_in[12];
    const float* pv2  = (const float*)d_in[13];
    const float* dW1  = (const float*)d_in[14];
    const float* db1  = (const float*)d_in[15];
    const float* dg1  = (const float*)d_in[16];
    const float* dbe1 = (const float*)d_in[17];
    const float* dm1  = (const float*)d_in[18];
    const float* dv1  = (const float*)d_in[19];
    const float* dW2  = (const float*)d_in[20];
    const float* db2  = (const float*)d_in[21];
    const float* dg2  = (const float*)d_in[22];
    const float* dbe2 = (const float*)d_in[23];
    const float* dm2  = (const float*)d_in[24];
    const float* dv2  = (const float*)d_in[25];
    const float* gum  = (const float*)d_in[26];

    // output layout (floats): xhat | entropies | latent | indices | zs
    float* out  = (float*)d_out;
    float* xhat = out;
    float* ent  = xhat + (size_t)MR * DD;
    float* lat  = ent  + (size_t)QN * MR;
    float* idxf = lat  + (size_t)QN * MR * NN;
    float* zs   = idxf + (size_t)QN * MR;

    // workspace layout
    char* wp = (char*)d_ws;
    float*  res   = (float*)wp;                 wp += (size_t)MR * DD * 4;
    float*  qo    = (float*)wp;                 wp += (size_t)MR * DD * 4;
    __bf16* Abf   = (__bf16*)wp;                wp += (size_t)MR * DD * 2;
    __bf16* hbf   = (__bf16*)wp;                wp += (size_t)MR * HH * 2;
    __bf16* qobf  = (__bf16*)wp;                wp += (size_t)MR * DD * 2;
    __bf16* h1bf  = (__bf16*)wp;                wp += (size_t)MR * 2 * DD * 2;
    __bf16* w1t   = (__bf16*)wp;                wp += (size_t)QN * DD * HH * 2;
    __bf16* w2t   = (__bf16*)wp;                wp += (size_t)QN * HH * NN * 2;
    __bf16* dw1t  = (__bf16*)wp;                wp += (size_t)DD * 2 * DD * 2;
    __bf16* dw2t  = (__bf16*)wp;                wp += (size_t)2 * DD * DD * 2;
    int*    wl    = (int*)wp;                   wp += (size_t)QN * MR * 4;
    int*    cnt   = (int*)wp;                   wp += 64;

    dim3 b256(256);

    // fused prep: all weight transposes + x conversion + cnt zeroing
    hipLaunchKernelGGL(prep, dim3(8960), b256, 0, stream,
        pW1, pW2, dW1, dW2, x, w1t, w2t, dw1t, dw2t, Abf, cnt);

    for (int i = 0; i < QN; ++i) {
        const int first = (i == 0), last = (i == QN - 1);
        hipLaunchKernelGGL((gemm_mfma<1>), dim3(HH / 128, MR / 128), b256, 0, stream,
            Abf, w1t + (size_t)i * DD * HH,
            pb1 + i * HH, pg1 + i * HH, pbe1 + i * HH, pm1 + i * HH, pv1 + i * HH,
            (float*)nullptr, hbf, HH, DD);
        float* z_i = zs + (size_t)i * MR * NN;
        hipLaunchKernelGGL((gemm_mfma<0>), dim3(NN / 128, MR / 128), b256, 0, stream,
            hbf, w2t + (size_t)i * HH * NN,
            pb2 + i * NN, pg2 + i * NN, pbe2 + i * NN, pm2 + i * NN, pv2 + i * NN,
            z_i, (__bf16*)nullptr, NN, HH);

        const float* Ain = (i == 0) ? x : res;
        hipLaunchKernelGGL(row_stats, dim3(MR), b256, 0, stream,
            z_i, gum + (size_t)i * MR * NN,
            ent + (size_t)i * MR, lat + (size_t)i * MR * NN, idxf + (size_t)i * MR,
            wl + (size_t)i * MR, cnt + i,
            Ain, cb + (size_t)i * NN * DD, res, qo, Abf, qobf, first, last);

        hipLaunchKernelGGL(recheck, dim3(256), b256, 0, stream,
            wl + (size_t)i * MR, cnt + i, gum + (size_t)i * MR * NN, Ain,
            pW1 + (size_t)i * DD * HH, pb1 + i * HH, pg1 + i * HH, pbe1 + i * HH,
            pm1 + i * HH, pv1 + i * HH,
            pW2 + (size_t)i * HH * NN, pb2 + i * NN, pg2 + i * NN, pbe2 + i * NN,
            pm2 + i * NN, pv2 + i * NN,
            idxf + (size_t)i * MR,
            cb + (size_t)i * NN * DD, res, qo, Abf, qobf, first, last);
    }
    // decoder
    hipLaunchKernelGGL((gemm_mfma<1>), dim3(2 * DD / 128, MR / 128), b256, 0, stream,
        qobf, dw1t, db1, dg1, dbe1, dm1, dv1, (float*)nullptr, h1bf, 2 * DD, DD);
    hipLaunchKernelGGL((gemm_mfma<0>), dim3(DD / 128, MR / 128), b256, 0, stream,
        h1bf, dw2t, db2, dg2, dbe2, dm2, dv2, xhat, (__bf16*)nullptr, DD, 2 * DD);
}